// Round 2
// baseline (2008.194 us; speedup 1.0000x reference)
//
#include <hip/hip_runtime.h>
#include <hip/hip_bf16.h>

typedef __attribute__((ext_vector_type(8))) short s16x8;
typedef __attribute__((ext_vector_type(4))) int   i32x4;
typedef __attribute__((ext_vector_type(4))) float f32x4;

#define NCAPS 4608
#define BATCH 128

// async global->LDS helper (16B per lane, wave-uniform LDS dest)
#define GLOAD_LDS16(gp, lp)                                                   \
  __builtin_amdgcn_global_load_lds(                                           \
      (const __attribute__((address_space(1))) void*)(gp),                    \
      (__attribute__((address_space(3))) void*)(lp), 16, 0, 0)

// ---------------------------------------------------------------------------
// conv2 weights: (9*9*256, 1024) f32 -> transposed bf16 (1024, 20736)
// ---------------------------------------------------------------------------
__global__ void transpose_w_kernel(const float* __restrict__ W,
                                   __hip_bfloat16* __restrict__ Wt) {
  __shared__ float tile[64][65];
  int kt = blockIdx.x * 64;   // k tile (0..20735)
  int ct = blockIdx.y * 64;   // co tile (0..1023)
  for (int i = threadIdx.x; i < 64 * 64; i += 256) {
    int r = i >> 6, c = i & 63;
    tile[r][c] = W[(size_t)(kt + r) * 1024 + ct + c];
  }
  __syncthreads();
  for (int i = threadIdx.x; i < 64 * 64; i += 256) {
    int r = i >> 6, c = i & 63;
    Wt[(size_t)(ct + r) * 20736 + kt + c] = __float2bfloat16(tile[c][r]);
  }
}

// ---------------------------------------------------------------------------
// conv1: (128,32,32,1) x (9,9,1,256) VALID stride1 + bias + relu -> bf16
// writes into ZERO-PADDED layout [b][31][31][256], interior at (+3,+3)
// (pad_lo=3, pad_hi=4 for conv2 SAME stride-2; borders pre-zeroed by memset)
// ---------------------------------------------------------------------------
__global__ void conv1_kernel(const float* __restrict__ x,
                             const float* __restrict__ w,
                             const float* __restrict__ bias,
                             __hip_bfloat16* __restrict__ outp) {
  int by = blockIdx.x;            // b*24 + y
  int b = by / 24, y = by % 24;
  __shared__ float patch[288];    // 9 rows x 32 cols
  for (int i = threadIdx.x; i < 288; i += 256) {
    int r = i >> 5, c = i & 31;
    patch[i] = x[(size_t)b * 1024 + (y + r) * 32 + c];
  }
  __syncthreads();
  int co = threadIdx.x;
  float bv = bias[co];
  float acc[24];
#pragma unroll
  for (int i = 0; i < 24; i++) acc[i] = bv;
#pragma unroll
  for (int ky = 0; ky < 9; ky++) {
    float row[32];
#pragma unroll
    for (int c = 0; c < 32; c++) row[c] = patch[ky * 32 + c];
#pragma unroll
    for (int kx = 0; kx < 9; kx++) {
      float wv = w[(ky * 9 + kx) * 256 + co];
#pragma unroll
      for (int xx = 0; xx < 24; xx++) acc[xx] += row[kx + xx] * wv;
    }
  }
  // padded store: [b][y+3][x+3][co]
  size_t obase = (((size_t)b * 31 + (y + 3)) * 31 + 3) * 256 + co;
#pragma unroll
  for (int xx = 0; xx < 24; xx++)
    outp[obase + (size_t)xx * 256] = __float2bfloat16(fmaxf(acc[xx], 0.f));
}

// ---------------------------------------------------------------------------
// conv2 as implicit GEMM, bf16 MFMA 16x16x32, m97 structure:
// 128x128 tile, BK=64, 4 waves (2x2), single-buffer LDS, 2 barriers/K-step,
// global_load_lds width=16 for BOTH operands (A from padded buffer -> no
// predication). Linear LDS (T2 swizzle is NULL at 128^2+2ph per regime gate).
// ---------------------------------------------------------------------------
__global__ __launch_bounds__(256)
void conv2_mfma_kernel(const __hip_bfloat16* __restrict__ Apad,  // [128][31][31][256]
                       const __hip_bfloat16* __restrict__ Wt,    // [1024][20736]
                       const float* __restrict__ bias,
                       float* __restrict__ U) {
  __shared__ __align__(16) __hip_bfloat16 As[128 * 64];
  __shared__ __align__(16) __hip_bfloat16 Bs[128 * 64];
  int bn = blockIdx.x;   // 0..7
  int bm = blockIdx.y;   // 0..143
  int tid = threadIdx.x;
  int lane = tid & 63, w = tid >> 6;
  int seg  = lane & 7;   // 16B segment within a row's 128B (8 bf16)
  int rsub = lane >> 3;  // 0..7

  // per-lane global source bases; rows r = w*32 + i*8 + rsub
  const __hip_bfloat16* abase[4];
  const __hip_bfloat16* bbase[4];
#pragma unroll
  for (int i = 0; i < 4; i++) {
    int r = w * 32 + i * 8 + rsub;
    int m = bm * 128 + r;
    int b = m / 144, rem = m % 144;
    int oy = rem / 12, ox = rem % 12;
    abase[i] = Apad + (((size_t)(b * 31 + oy * 2)) * 31 + ox * 2) * 256 + seg * 8;
    int n = bn * 128 + r;
    bbase[i] = Wt + (size_t)n * 20736 + seg * 8;
  }

  f32x4 acc[4][4];
#pragma unroll
  for (int mi = 0; mi < 4; mi++)
#pragma unroll
    for (int ni = 0; ni < 4; ni++)
#pragma unroll
      for (int r = 0; r < 4; r++) acc[mi][ni][r] = 0.f;

  int wm = w >> 1, wn = w & 1;
  int lrow = lane & 15;
  int lke = (lane >> 4) * 8;   // element offset of this lane's 8 bf16 within K=32

  for (int pos = 0; pos < 81; pos++) {
    int ky = pos / 9, kx = pos % 9;
    size_t aoff = (size_t)(ky * 31 + kx) * 256;
    size_t boff = (size_t)pos * 256;
#pragma unroll
    for (int ci0 = 0; ci0 < 256; ci0 += 64) {
#pragma unroll
      for (int i = 0; i < 4; i++) {
        GLOAD_LDS16(abase[i] + aoff + ci0, &As[(w * 32 + i * 8) * 64]);
        GLOAD_LDS16(bbase[i] + boff + ci0, &Bs[(w * 32 + i * 8) * 64]);
      }
      __syncthreads();
#pragma unroll
      for (int ksub = 0; ksub < 2; ksub++) {
        s16x8 af[4], bf[4];
#pragma unroll
        for (int mi = 0; mi < 4; mi++)
          af[mi] = *(const s16x8*)(As + (wm * 64 + mi * 16 + lrow) * 64 + ksub * 32 + lke);
#pragma unroll
        for (int ni = 0; ni < 4; ni++)
          bf[ni] = *(const s16x8*)(Bs + (wn * 64 + ni * 16 + lrow) * 64 + ksub * 32 + lke);
#pragma unroll
        for (int mi = 0; mi < 4; mi++)
#pragma unroll
          for (int ni = 0; ni < 4; ni++)
            acc[mi][ni] = __builtin_amdgcn_mfma_f32_16x16x32_bf16(
                af[mi], bf[ni], acc[mi][ni], 0, 0, 0);
      }
      __syncthreads();
    }
  }

  // epilogue: D row = (lane>>4)*4 + reg, col = lane&15  [measured m89/m91]
#pragma unroll
  for (int mi = 0; mi < 4; mi++) {
    int mg = bm * 128 + wm * 64 + mi * 16 + ((lane >> 4) << 2);
#pragma unroll
    for (int ni = 0; ni < 4; ni++) {
      int ng = bn * 128 + wn * 64 + ni * 16 + (lane & 15);
      float bv = bias[ng];
#pragma unroll
      for (int r = 0; r < 4; r++)
        U[(size_t)(mg + r) * 1024 + ng] = acc[mi][ni][r] + bv;
    }
  }
}

// ---------------------------------------------------------------------------
// u_hat[b,n,kd] = sum_p w[n,kd,p] * u[b,n,p]; one block per capsule n.
// ---------------------------------------------------------------------------
__global__ void uhat_kernel(const float* __restrict__ u,
                            const float* __restrict__ w,
                            float* __restrict__ uhat) {
  int n = blockIdx.x;
  __shared__ float wsm[32 * 33];
  int t = threadIdx.x;
  for (int i = t; i < 1024; i += 256)
    wsm[(i >> 5) * 33 + (i & 31)] = w[(size_t)n * 1024 + i];
  __syncthreads();
  int kd = t & 31, bs = t >> 5;
  float wr[32];
#pragma unroll
  for (int p = 0; p < 32; p++) wr[p] = wsm[kd * 33 + p];
  for (int bp = 0; bp < 16; bp++) {
    int b = bp * 8 + bs;
    size_t off = ((size_t)b * NCAPS + n) * 32 + kd;
    float uval = u[off];
    float acc = 0.f;
#pragma unroll
    for (int p = 0; p < 32; p++) acc += wr[p] * __shfl(uval, p, 32);
    uhat[off] = acc;
  }
}

// ---------------------------------------------------------------------------
// routing pass: ITER 0 -> c = 0.5 (softmax of zeros)
//               ITER 1 -> a1 = u_hat.v1 (stored), c = softmax_k(a1)
//               ITER 2 -> c = softmax_k(a1 + u_hat.v2)
// emits per-(b, n-chunk) partial sums of c*u_hat (deterministic 2-stage reduce)
// ---------------------------------------------------------------------------
template <int ITER>
__global__ void routing_kernel(const float* __restrict__ uhat,
                               const float* __restrict__ v,
                               float* __restrict__ a1,
                               float* __restrict__ Spart) {
  int b = blockIdx.y;
  int t = threadIdx.x;
  int n = blockIdx.x * 256 + t;
  __shared__ float vs[32];
  __shared__ float wsum[4][33];
  if (ITER > 0) {
    if (t < 32) vs[t] = v[b * 32 + t];
    __syncthreads();
  }
  float uh[32];
  const float* up = uhat + ((size_t)b * NCAPS + n) * 32;
#pragma unroll
  for (int i = 0; i < 32; i += 4) {
    f32x4 tmp = *(const f32x4*)(up + i);
    uh[i + 0] = tmp[0]; uh[i + 1] = tmp[1];
    uh[i + 2] = tmp[2]; uh[i + 3] = tmp[3];
  }
  float c0 = 0.5f, c1 = 0.5f;
  if (ITER > 0) {
    float d0 = 0.f, d1 = 0.f;
#pragma unroll
    for (int d = 0; d < 16; d++) { d0 += uh[d] * vs[d]; d1 += uh[16 + d] * vs[16 + d]; }
    float b0, b1;
    size_t ai = ((size_t)b * NCAPS + n) * 2;
    if (ITER == 1) {
      a1[ai] = d0; a1[ai + 1] = d1;
      b0 = d0; b1 = d1;
    } else {
      b0 = a1[ai] + d0; b1 = a1[ai + 1] + d1;
    }
    float mx = fmaxf(b0, b1);
    float e0 = __expf(b0 - mx), e1 = __expf(b1 - mx);
    float inv = 1.f / (e0 + e1);
    c0 = e0 * inv; c1 = e1 * inv;
  }
  float val[32];
#pragma unroll
  for (int i = 0; i < 16; i++) { val[i] = c0 * uh[i]; val[16 + i] = c1 * uh[16 + i]; }
#pragma unroll
  for (int m = 1; m < 64; m <<= 1) {
#pragma unroll
    for (int i = 0; i < 32; i++) val[i] += __shfl_xor(val[i], m, 64);
  }
  int lane = t & 63, wid = t >> 6;
  if (lane == 0) {
#pragma unroll
    for (int i = 0; i < 32; i++) wsum[wid][i] = val[i];
  }
  __syncthreads();
  if (t < 32)
    Spart[((size_t)b * 18 + blockIdx.x) * 32 + t] =
        wsum[0][t] + wsum[1][t] + wsum[2][t] + wsum[3][t];
}

// ---------------------------------------------------------------------------
// squash: reduce 18 partials, v = |s|^2/(1+|s|^2) * s/(|s|+eps)
// one block, 256 threads = (b,k) pairs. Final call also writes d_out v + mask.
// ---------------------------------------------------------------------------
__global__ void squash_kernel(const float* __restrict__ Spart,
                              float* __restrict__ v,
                              const float* __restrict__ y,
                              float* __restrict__ vmask,
                              float* __restrict__ vout) {
  int t = threadIdx.x;            // t = b*2 + k
  float s[16];
#pragma unroll
  for (int d = 0; d < 16; d++) s[d] = 0.f;
  const float* p = Spart + (size_t)(t >> 1) * 18 * 32 + (t & 1) * 16;
  for (int ch = 0; ch < 18; ch++) {
#pragma unroll
    for (int d = 0; d < 16; d++) s[d] += p[ch * 32 + d];
  }
  float n2 = 0.f;
#pragma unroll
  for (int d = 0; d < 16; d++) n2 += s[d] * s[d];
  float nrm = sqrtf(n2);
  float f = n2 / (1.f + n2) / (nrm + 1e-7f);
#pragma unroll
  for (int d = 0; d < 16; d++) {
    float vd = s[d] * f;
    v[t * 16 + d] = vd;
    if (vout != nullptr) {
      vout[t * 16 + d] = vd;
      vmask[t * 16 + d] = y[t] * vd;
    }
  }
}

// ---------------------------------------------------------------------------
// decoder dense layer: Y[128,N] = act(X[128,K] @ Wd[K,N] + bias)
// block: 256 thr = 64 cols x 4 row-groups; each thread 32 rows. grid: N/64.
// ACT: 1 = relu, 2 = sigmoid
// ---------------------------------------------------------------------------
template <int ACT>
__global__ void dense_kernel(const float* __restrict__ X,
                             const float* __restrict__ Wd,
                             const float* __restrict__ bias,
                             float* __restrict__ Y, int K, int N) {
  __shared__ float xs[32][132];   // [kk][b]
  int tx = threadIdx.x & 63, ty = threadIdx.x >> 6;
  int j = blockIdx.x * 64 + tx;
  float acc[32];
#pragma unroll
  for (int i = 0; i < 32; i++) acc[i] = 0.f;
  for (int kc = 0; kc < K; kc += 32) {
    for (int i = threadIdx.x; i < 128 * 32; i += 256) {
      int bb = i >> 5, kk = i & 31;
      xs[kk][bb] = X[(size_t)bb * K + kc + kk];
    }
    __syncthreads();
    for (int kk = 0; kk < 32; kk++) {
      float wvv = Wd[(size_t)(kc + kk) * N + j];
#pragma unroll
      for (int i = 0; i < 32; i++) acc[i] += xs[kk][ty + 4 * i] * wvv;
    }
    __syncthreads();
  }
  float bv = bias[j];
#pragma unroll
  for (int i = 0; i < 32; i++) {
    float r = acc[i] + bv;
    if (ACT == 1) r = fmaxf(r, 0.f);
    else          r = 1.f / (1.f + __expf(-r));
    Y[(size_t)(ty + 4 * i) * N + j] = r;
  }
}

// ---------------------------------------------------------------------------
extern "C" void kernel_launch(void* const* d_in, const int* in_sizes, int n_in,
                              void* d_out, int out_size, void* d_ws, size_t ws_size,
                              hipStream_t stream) {
  const float* input_x = (const float*)d_in[0];
  const float* y       = (const float*)d_in[1];
  const float* conv1_w = (const float*)d_in[2];
  const float* conv1_b = (const float*)d_in[3];
  const float* conv2_w = (const float*)d_in[4];
  const float* conv2_b = (const float*)d_in[5];
  const float* w_caps  = (const float*)d_in[6];
  const float* d1_w    = (const float*)d_in[7];
  const float* d1_b    = (const float*)d_in[8];
  const float* d2_w    = (const float*)d_in[9];
  const float* d2_b    = (const float*)d_in[10];
  const float* d3_w    = (const float*)d_in[11];
  const float* d3_b    = (const float*)d_in[12];
  float* out = (float*)d_out;

  // workspace carve-up
  char* ws = (char*)d_ws;
  size_t apad_bytes = (size_t)128 * 31 * 31 * 256 * 2;                 // 62.9 MB
  __hip_bfloat16* Apad = (__hip_bfloat16*)ws; ws += (apad_bytes + 255) & ~255ull;
  __hip_bfloat16* Wt   = (__hip_bfloat16*)ws; ws += 42467328;          // 1024*20736 bf16
  float* u     = (float*)ws; ws += 75497472;                           // 128*4608*32 f32
  float* uhat  = (float*)ws; ws += 75497472;                           // 128*4608*32 f32
  float* a1    = (float*)ws; ws += 4718592;                            // 128*4608*2 f32
  float* Spart = (float*)ws; ws += 294912;                             // 128*18*32 f32
  float* vbuf  = (float*)ws; ws += 16384;                              // 128*32 f32
  float* vmask = (float*)ws; ws += 16384;                              // 128*32 f32
  float* h1    = (float*)ws; ws += 131072;                             // 128*256 f32
  float* h2    = (float*)ws; ws += 262144;                             // 128*512 f32

  hipMemsetAsync(Apad, 0, apad_bytes, stream);   // zero padding borders
  transpose_w_kernel<<<dim3(324, 16), 256, 0, stream>>>(conv2_w, Wt);
  conv1_kernel<<<3072, 256, 0, stream>>>(input_x, conv1_w, conv1_b, Apad);
  conv2_mfma_kernel<<<dim3(8, 144), 256, 0, stream>>>(Apad, Wt, conv2_b, u);
  uhat_kernel<<<NCAPS, 256, 0, stream>>>(u, w_caps, uhat);

  routing_kernel<0><<<dim3(18, 128), 256, 0, stream>>>(uhat, nullptr, nullptr, Spart);
  squash_kernel<<<1, 256, 0, stream>>>(Spart, vbuf, nullptr, nullptr, nullptr);
  routing_kernel<1><<<dim3(18, 128), 256, 0, stream>>>(uhat, vbuf, a1, Spart);
  squash_kernel<<<1, 256, 0, stream>>>(Spart, vbuf, nullptr, nullptr, nullptr);
  routing_kernel<2><<<dim3(18, 128), 256, 0, stream>>>(uhat, vbuf, a1, Spart);
  // final squash: writes v into d_out[0:4096] and masked v for the decoder
  squash_kernel<<<1, 256, 0, stream>>>(Spart, vbuf, y, vmask, out);

  dense_kernel<1><<<4, 256, 0, stream>>>(vmask, d1_w, d1_b, h1, 32, 256);
  dense_kernel<1><<<8, 256, 0, stream>>>(h1, d2_w, d2_b, h2, 256, 512);
  dense_kernel<2><<<16, 256, 0, stream>>>(h2, d3_w, d3_b, out + 4096, 512, 1024);
}

// Round 3
// 1739.860 us; speedup vs baseline: 1.1542x; 1.1542x over previous
//
#include <hip/hip_runtime.h>
#include <hip/hip_bf16.h>

typedef __attribute__((ext_vector_type(8))) short s16x8;
typedef __attribute__((ext_vector_type(4))) int   i32x4;
typedef __attribute__((ext_vector_type(4))) float f32x4;

#define NCAPS 4608
#define BATCH 128

// async global->LDS helper (16B per lane, wave-uniform LDS dest)
#define GLOAD_LDS16(gp, lp)                                                   \
  __builtin_amdgcn_global_load_lds(                                           \
      (const __attribute__((address_space(1))) void*)(gp),                    \
      (__attribute__((address_space(3))) void*)(lp), 16, 0, 0)

// ---------------------------------------------------------------------------
// conv2 weights: (9*9*256, 1024) f32 -> transposed bf16 (1024, 20736)
// ---------------------------------------------------------------------------
__global__ void transpose_w_kernel(const float* __restrict__ W,
                                   __hip_bfloat16* __restrict__ Wt) {
  __shared__ float tile[64][65];
  int kt = blockIdx.x * 64;   // k tile (0..20735)
  int ct = blockIdx.y * 64;   // co tile (0..1023)
  for (int i = threadIdx.x; i < 64 * 64; i += 256) {
    int r = i >> 6, c = i & 63;
    tile[r][c] = W[(size_t)(kt + r) * 1024 + ct + c];
  }
  __syncthreads();
  for (int i = threadIdx.x; i < 64 * 64; i += 256) {
    int r = i >> 6, c = i & 63;
    Wt[(size_t)(ct + r) * 20736 + kt + c] = __float2bfloat16(tile[c][r]);
  }
}

// ---------------------------------------------------------------------------
// conv1: (128,32,32,1) x (9,9,1,256) VALID stride1 + bias + relu -> bf16
// writes into ZERO-PADDED layout [b][31][31][256], interior at (+3,+3)
// ---------------------------------------------------------------------------
__global__ void conv1_kernel(const float* __restrict__ x,
                             const float* __restrict__ w,
                             const float* __restrict__ bias,
                             __hip_bfloat16* __restrict__ outp) {
  int by = blockIdx.x;            // b*24 + y
  int b = by / 24, y = by % 24;
  __shared__ float patch[288];    // 9 rows x 32 cols
  for (int i = threadIdx.x; i < 288; i += 256) {
    int r = i >> 5, c = i & 31;
    patch[i] = x[(size_t)b * 1024 + (y + r) * 32 + c];
  }
  __syncthreads();
  int co = threadIdx.x;
  float bv = bias[co];
  float acc[24];
#pragma unroll
  for (int i = 0; i < 24; i++) acc[i] = bv;
#pragma unroll
  for (int ky = 0; ky < 9; ky++) {
    float row[32];
#pragma unroll
    for (int c = 0; c < 32; c++) row[c] = patch[ky * 32 + c];
#pragma unroll
    for (int kx = 0; kx < 9; kx++) {
      float wv = w[(ky * 9 + kx) * 256 + co];
#pragma unroll
      for (int xx = 0; xx < 24; xx++) acc[xx] += row[kx + xx] * wv;
    }
  }
  // padded store: [b][y+3][x+3][co]
  size_t obase = (((size_t)b * 31 + (y + 3)) * 31 + 3) * 256 + co;
#pragma unroll
  for (int xx = 0; xx < 24; xx++)
    outp[obase + (size_t)xx * 256] = __float2bfloat16(fmaxf(acc[xx], 0.f));
}

// ---------------------------------------------------------------------------
// conv2 as implicit GEMM, bf16 MFMA 16x16x32, m97 structure + rule-#21 swizzle:
// global_load_lds writes LINEAR LDS; the per-lane GLOBAL source chunk is
// pre-permuted (seg ^= row&7), and the ds_read applies the same involution
// (chunk ^= row&7). Net: conflict-free ds_read_b128 (2 lanes/bank) with DMA
// staging. 128x128 tile, BK=64, 4 waves (2x2), 2 barriers/K-step.
// ---------------------------------------------------------------------------
__global__ __launch_bounds__(256)
void conv2_mfma_kernel(const __hip_bfloat16* __restrict__ Apad,  // [128][31][31][256]
                       const __hip_bfloat16* __restrict__ Wt,    // [1024][20736]
                       const float* __restrict__ bias,
                       float* __restrict__ U) {
  __shared__ __align__(16) __hip_bfloat16 As[128 * 64];
  __shared__ __align__(16) __hip_bfloat16 Bs[128 * 64];
  int bn = blockIdx.x;   // 0..7
  int bm = blockIdx.y;   // 0..143
  int tid = threadIdx.x;
  int lane = tid & 63, w = tid >> 6;
  int seg  = lane & 7;   // 16B segment within a row's 128B (8 bf16)
  int rsub = lane >> 3;  // 0..7  == (row & 7) for this lane's staged row
  int sseg = seg ^ (rsub & 7);   // pre-swizzled source chunk

  // per-lane global source bases; rows r = w*32 + i*8 + rsub
  const __hip_bfloat16* abase[4];
  const __hip_bfloat16* bbase[4];
#pragma unroll
  for (int i = 0; i < 4; i++) {
    int r = w * 32 + i * 8 + rsub;
    int m = bm * 128 + r;
    int b = m / 144, rem = m % 144;
    int oy = rem / 12, ox = rem % 12;
    abase[i] = Apad + (((size_t)(b * 31 + oy * 2)) * 31 + ox * 2) * 256 + sseg * 8;
    int n = bn * 128 + r;
    bbase[i] = Wt + (size_t)n * 20736 + sseg * 8;
  }

  f32x4 acc[4][4];
#pragma unroll
  for (int mi = 0; mi < 4; mi++)
#pragma unroll
    for (int ni = 0; ni < 4; ni++)
#pragma unroll
      for (int r = 0; r < 4; r++) acc[mi][ni][r] = 0.f;

  int wm = w >> 1, wn = w & 1;
  int lrow = lane & 15;
  int lq = lane >> 4;          // quarter: which 8-elem chunk within K=32

  for (int pos = 0; pos < 81; pos++) {
    int ky = pos / 9, kx = pos % 9;
    size_t aoff = (size_t)(ky * 31 + kx) * 256;
    size_t boff = (size_t)pos * 256;
#pragma unroll
    for (int ci0 = 0; ci0 < 256; ci0 += 64) {
#pragma unroll
      for (int i = 0; i < 4; i++) {
        GLOAD_LDS16(abase[i] + aoff + ci0, &As[(w * 32 + i * 8) * 64]);
        GLOAD_LDS16(bbase[i] + boff + ci0, &Bs[(w * 32 + i * 8) * 64]);
      }
      __syncthreads();
#pragma unroll
      for (int ksub = 0; ksub < 2; ksub++) {
        s16x8 af[4], bf[4];
#pragma unroll
        for (int mi = 0; mi < 4; mi++) {
          int row = wm * 64 + mi * 16 + lrow;
          int c = (ksub * 4 + lq) ^ (row & 7);          // swizzled read chunk
          af[mi] = *(const s16x8*)(As + row * 64 + c * 8);
        }
#pragma unroll
        for (int ni = 0; ni < 4; ni++) {
          int row = wn * 64 + ni * 16 + lrow;
          int c = (ksub * 4 + lq) ^ (row & 7);
          bf[ni] = *(const s16x8*)(Bs + row * 64 + c * 8);
        }
#pragma unroll
        for (int mi = 0; mi < 4; mi++)
#pragma unroll
          for (int ni = 0; ni < 4; ni++)
            acc[mi][ni] = __builtin_amdgcn_mfma_f32_16x16x32_bf16(
                af[mi], bf[ni], acc[mi][ni], 0, 0, 0);
      }
      __syncthreads();
    }
  }

  // epilogue: D row = (lane>>4)*4 + reg, col = lane&15  [measured m89/m91]
#pragma unroll
  for (int mi = 0; mi < 4; mi++) {
    int mg = bm * 128 + wm * 64 + mi * 16 + ((lane >> 4) << 2);
#pragma unroll
    for (int ni = 0; ni < 4; ni++) {
      int ng = bn * 128 + wn * 64 + ni * 16 + (lane & 15);
      float bv = bias[ng];
#pragma unroll
      for (int r = 0; r < 4; r++)
        U[(size_t)(mg + r) * 1024 + ng] = acc[mi][ni][r] + bv;
    }
  }
}

// ---------------------------------------------------------------------------
// u_hat[b,n,kd] = sum_p w[n,kd,p] * u[b,n,p]; one block per capsule n.
// ---------------------------------------------------------------------------
__global__ void uhat_kernel(const float* __restrict__ u,
                            const float* __restrict__ w,
                            float* __restrict__ uhat) {
  int n = blockIdx.x;
  __shared__ float wsm[32 * 33];
  int t = threadIdx.x;
  for (int i = t; i < 1024; i += 256)
    wsm[(i >> 5) * 33 + (i & 31)] = w[(size_t)n * 1024 + i];
  __syncthreads();
  int kd = t & 31, bs = t >> 5;
  float wr[32];
#pragma unroll
  for (int p = 0; p < 32; p++) wr[p] = wsm[kd * 33 + p];
  for (int bp = 0; bp < 16; bp++) {
    int b = bp * 8 + bs;
    size_t off = ((size_t)b * NCAPS + n) * 32 + kd;
    float uval = u[off];
    float acc = 0.f;
#pragma unroll
    for (int p = 0; p < 32; p++) acc += wr[p] * __shfl(uval, p, 32);
    uhat[off] = acc;
  }
}

// ---------------------------------------------------------------------------
// routing pass: ITER 0 -> c = 0.5 (softmax of zeros)
//               ITER 1 -> a1 = u_hat.v1 (stored), c = softmax_k(a1)
//               ITER 2 -> c = softmax_k(a1 + u_hat.v2)
// ---------------------------------------------------------------------------
template <int ITER>
__global__ void routing_kernel(const float* __restrict__ uhat,
                               const float* __restrict__ v,
                               float* __restrict__ a1,
                               float* __restrict__ Spart) {
  int b = blockIdx.y;
  int t = threadIdx.x;
  int n = blockIdx.x * 256 + t;
  __shared__ float vs[32];
  __shared__ float wsum[4][33];
  if (ITER > 0) {
    if (t < 32) vs[t] = v[b * 32 + t];
    __syncthreads();
  }
  float uh[32];
  const float* up = uhat + ((size_t)b * NCAPS + n) * 32;
#pragma unroll
  for (int i = 0; i < 32; i += 4) {
    f32x4 tmp = *(const f32x4*)(up + i);
    uh[i + 0] = tmp[0]; uh[i + 1] = tmp[1];
    uh[i + 2] = tmp[2]; uh[i + 3] = tmp[3];
  }
  float c0 = 0.5f, c1 = 0.5f;
  if (ITER > 0) {
    float d0 = 0.f, d1 = 0.f;
#pragma unroll
    for (int d = 0; d < 16; d++) { d0 += uh[d] * vs[d]; d1 += uh[16 + d] * vs[16 + d]; }
    float b0, b1;
    size_t ai = ((size_t)b * NCAPS + n) * 2;
    if (ITER == 1) {
      a1[ai] = d0; a1[ai + 1] = d1;
      b0 = d0; b1 = d1;
    } else {
      b0 = a1[ai] + d0; b1 = a1[ai + 1] + d1;
    }
    float mx = fmaxf(b0, b1);
    float e0 = __expf(b0 - mx), e1 = __expf(b1 - mx);
    float inv = 1.f / (e0 + e1);
    c0 = e0 * inv; c1 = e1 * inv;
  }
  float val[32];
#pragma unroll
  for (int i = 0; i < 16; i++) { val[i] = c0 * uh[i]; val[16 + i] = c1 * uh[16 + i]; }
#pragma unroll
  for (int m = 1; m < 64; m <<= 1) {
#pragma unroll
    for (int i = 0; i < 32; i++) val[i] += __shfl_xor(val[i], m, 64);
  }
  int lane = t & 63, wid = t >> 6;
  if (lane == 0) {
#pragma unroll
    for (int i = 0; i < 32; i++) wsum[wid][i] = val[i];
  }
  __syncthreads();
  if (t < 32)
    Spart[((size_t)b * 18 + blockIdx.x) * 32 + t] =
        wsum[0][t] + wsum[1][t] + wsum[2][t] + wsum[3][t];
}

// ---------------------------------------------------------------------------
// squash: reduce 18 partials, v = |s|^2/(1+|s|^2) * s/(|s|+eps)
// ---------------------------------------------------------------------------
__global__ void squash_kernel(const float* __restrict__ Spart,
                              float* __restrict__ v,
                              const float* __restrict__ y,
                              float* __restrict__ vmask,
                              float* __restrict__ vout) {
  int t = threadIdx.x;            // t = b*2 + k
  float s[16];
#pragma unroll
  for (int d = 0; d < 16; d++) s[d] = 0.f;
  const float* p = Spart + (size_t)(t >> 1) * 18 * 32 + (t & 1) * 16;
  for (int ch = 0; ch < 18; ch++) {
#pragma unroll
    for (int d = 0; d < 16; d++) s[d] += p[ch * 32 + d];
  }
  float n2 = 0.f;
#pragma unroll
  for (int d = 0; d < 16; d++) n2 += s[d] * s[d];
  float nrm = sqrtf(n2);
  float f = n2 / (1.f + n2) / (nrm + 1e-7f);
#pragma unroll
  for (int d = 0; d < 16; d++) {
    float vd = s[d] * f;
    v[t * 16 + d] = vd;
    if (vout != nullptr) {
      vout[t * 16 + d] = vd;
      vmask[t * 16 + d] = y[t] * vd;
    }
  }
}

// ---------------------------------------------------------------------------
// decoder dense layer: Y[128,N] = act(X[128,K] @ Wd[K,N] + bias)
// ---------------------------------------------------------------------------
template <int ACT>
__global__ void dense_kernel(const float* __restrict__ X,
                             const float* __restrict__ Wd,
                             const float* __restrict__ bias,
                             float* __restrict__ Y, int K, int N) {
  __shared__ float xs[32][132];   // [kk][b]
  int tx = threadIdx.x & 63, ty = threadIdx.x >> 6;
  int j = blockIdx.x * 64 + tx;
  float acc[32];
#pragma unroll
  for (int i = 0; i < 32; i++) acc[i] = 0.f;
  for (int kc = 0; kc < K; kc += 32) {
    for (int i = threadIdx.x; i < 128 * 32; i += 256) {
      int bb = i >> 5, kk = i & 31;
      xs[kk][bb] = X[(size_t)bb * K + kc + kk];
    }
    __syncthreads();
    for (int kk = 0; kk < 32; kk++) {
      float wvv = Wd[(size_t)(kc + kk) * N + j];
#pragma unroll
      for (int i = 0; i < 32; i++) acc[i] += xs[kk][ty + 4 * i] * wvv;
    }
    __syncthreads();
  }
  float bv = bias[j];
#pragma unroll
  for (int i = 0; i < 32; i++) {
    float r = acc[i] + bv;
    if (ACT == 1) r = fmaxf(r, 0.f);
    else          r = 1.f / (1.f + __expf(-r));
    Y[(size_t)(ty + 4 * i) * N + j] = r;
  }
}

// ---------------------------------------------------------------------------
extern "C" void kernel_launch(void* const* d_in, const int* in_sizes, int n_in,
                              void* d_out, int out_size, void* d_ws, size_t ws_size,
                              hipStream_t stream) {
  const float* input_x = (const float*)d_in[0];
  const float* y       = (const float*)d_in[1];
  const float* conv1_w = (const float*)d_in[2];
  const float* conv1_b = (const float*)d_in[3];
  const float* conv2_w = (const float*)d_in[4];
  const float* conv2_b = (const float*)d_in[5];
  const float* w_caps  = (const float*)d_in[6];
  const float* d1_w    = (const float*)d_in[7];
  const float* d1_b    = (const float*)d_in[8];
  const float* d2_w    = (const float*)d_in[9];
  const float* d2_b    = (const float*)d_in[10];
  const float* d3_w    = (const float*)d_in[11];
  const float* d3_b    = (const float*)d_in[12];
  float* out = (float*)d_out;

  // workspace carve-up
  char* ws = (char*)d_ws;
  size_t apad_bytes = (size_t)128 * 31 * 31 * 256 * 2;                 // 62.9 MB
  __hip_bfloat16* Apad = (__hip_bfloat16*)ws; ws += (apad_bytes + 255) & ~255ull;
  __hip_bfloat16* Wt   = (__hip_bfloat16*)ws; ws += 42467328;          // 1024*20736 bf16
  float* u     = (float*)ws; ws += 75497472;                           // 128*4608*32 f32
  float* uhat  = (float*)ws; ws += 75497472;                           // 128*4608*32 f32
  float* a1    = (float*)ws; ws += 4718592;                            // 128*4608*2 f32
  float* Spart = (float*)ws; ws += 294912;                             // 128*18*32 f32
  float* vbuf  = (float*)ws; ws += 16384;                              // 128*32 f32
  float* vmask = (float*)ws; ws += 16384;                              // 128*32 f32
  float* h1    = (float*)ws; ws += 131072;                             // 128*256 f32
  float* h2    = (float*)ws; ws += 262144;                             // 128*512 f32

  hipMemsetAsync(Apad, 0, apad_bytes, stream);   // zero padding borders
  transpose_w_kernel<<<dim3(324, 16), 256, 0, stream>>>(conv2_w, Wt);
  conv1_kernel<<<3072, 256, 0, stream>>>(input_x, conv1_w, conv1_b, Apad);
  conv2_mfma_kernel<<<dim3(8, 144), 256, 0, stream>>>(Apad, Wt, conv2_b, u);
  uhat_kernel<<<NCAPS, 256, 0, stream>>>(u, w_caps, uhat);

  routing_kernel<0><<<dim3(18, 128), 256, 0, stream>>>(uhat, nullptr, nullptr, Spart);
  squash_kernel<<<1, 256, 0, stream>>>(Spart, vbuf, nullptr, nullptr, nullptr);
  routing_kernel<1><<<dim3(18, 128), 256, 0, stream>>>(uhat, vbuf, a1, Spart);
  squash_kernel<<<1, 256, 0, stream>>>(Spart, vbuf, nullptr, nullptr, nullptr);
  routing_kernel<2><<<dim3(18, 128), 256, 0, stream>>>(uhat, vbuf, a1, Spart);
  // final squash: writes v into d_out[0:4096] and masked v for the decoder
  squash_kernel<<<1, 256, 0, stream>>>(Spart, vbuf, y, vmask, out);

  dense_kernel<1><<<4, 256, 0, stream>>>(vmask, d1_w, d1_b, h1, 32, 256);
  dense_kernel<1><<<8, 256, 0, stream>>>(h1, d2_w, d2_b, h2, 256, 512);
  dense_kernel<2><<<16, 256, 0, stream>>>(h2, d3_w, d3_b, out + 4096, 512, 1024);
}

// Round 4
// 1701.444 us; speedup vs baseline: 1.1803x; 1.0226x over previous
//
#include <hip/hip_runtime.h>
#include <hip/hip_bf16.h>

typedef __attribute__((ext_vector_type(8))) short s16x8;
typedef __attribute__((ext_vector_type(4))) int   i32x4;
typedef __attribute__((ext_vector_type(4))) float f32x4;

#define NCAPS 4608
#define BATCH 128

// async global->LDS helper (16B per lane, wave-uniform LDS dest)
#define GLOAD_LDS16(gp, lp)                                                   \
  __builtin_amdgcn_global_load_lds(                                           \
      (const __attribute__((address_space(1))) void*)(gp),                    \
      (__attribute__((address_space(3))) void*)(lp), 16, 0, 0)

// ---------------------------------------------------------------------------
// conv2 weights: (9*9*256, 1024) f32 -> transposed bf16 (1024, 20736)
// ---------------------------------------------------------------------------
__global__ void transpose_w_kernel(const float* __restrict__ W,
                                   __hip_bfloat16* __restrict__ Wt) {
  __shared__ float tile[64][65];
  int kt = blockIdx.x * 64;   // k tile (0..20735)
  int ct = blockIdx.y * 64;   // co tile (0..1023)
  for (int i = threadIdx.x; i < 64 * 64; i += 256) {
    int r = i >> 6, c = i & 63;
    tile[r][c] = W[(size_t)(kt + r) * 1024 + ct + c];
  }
  __syncthreads();
  for (int i = threadIdx.x; i < 64 * 64; i += 256) {
    int r = i >> 6, c = i & 63;
    Wt[(size_t)(ct + r) * 20736 + kt + c] = __float2bfloat16(tile[c][r]);
  }
}

// ---------------------------------------------------------------------------
// conv1: (128,32,32,1) x (9,9,1,256) VALID stride1 + bias + relu -> bf16
// writes into ZERO-PADDED layout [b][31][31][256], interior at (+3,+3)
// ---------------------------------------------------------------------------
__global__ void conv1_kernel(const float* __restrict__ x,
                             const float* __restrict__ w,
                             const float* __restrict__ bias,
                             __hip_bfloat16* __restrict__ outp) {
  int by = blockIdx.x;            // b*24 + y
  int b = by / 24, y = by % 24;
  __shared__ float patch[288];    // 9 rows x 32 cols
  for (int i = threadIdx.x; i < 288; i += 256) {
    int r = i >> 5, c = i & 31;
    patch[i] = x[(size_t)b * 1024 + (y + r) * 32 + c];
  }
  __syncthreads();
  int co = threadIdx.x;
  float bv = bias[co];
  float acc[24];
#pragma unroll
  for (int i = 0; i < 24; i++) acc[i] = bv;
#pragma unroll
  for (int ky = 0; ky < 9; ky++) {
    float row[32];
#pragma unroll
    for (int c = 0; c < 32; c++) row[c] = patch[ky * 32 + c];
#pragma unroll
    for (int kx = 0; kx < 9; kx++) {
      float wv = w[(ky * 9 + kx) * 256 + co];
#pragma unroll
      for (int xx = 0; xx < 24; xx++) acc[xx] += row[kx + xx] * wv;
    }
  }
  // padded store: [b][y+3][x+3][co]
  size_t obase = (((size_t)b * 31 + (y + 3)) * 31 + 3) * 256 + co;
#pragma unroll
  for (int xx = 0; xx < 24; xx++)
    outp[obase + (size_t)xx * 256] = __float2bfloat16(fmaxf(acc[xx], 0.f));
}

// ---------------------------------------------------------------------------
// conv2 as implicit GEMM, bf16 MFMA 16x16x32, m97 structure + rule-#21 swizzle.
// NEW (R4): 1D grid 1152 with super-row + XCD-chunked mapping:
//   l = blockIdx.x; s = l/128 (super-row of 16 bm x 8 bn); w0 = l%128;
//   xcd = w0%8 (HW round-robins consecutive l across XCDs);
//   j = w0/8; bm = s*16 + xcd*2 + (j&1); bn = j>>1.
// Each XCD gets 2 bm-tiles (A ~1 MB -> its private L2) x all 8 bn; the 8
// B-panels (42 MB total) stay L3-resident -> FETCH should collapse.
// Bijective: (s in [0,9)) x (xcd in [0,8)) x (j in [0,16)) = 1152. 
// ---------------------------------------------------------------------------
__global__ __launch_bounds__(256)
void conv2_mfma_kernel(const __hip_bfloat16* __restrict__ Apad,  // [128][31][31][256]
                       const __hip_bfloat16* __restrict__ Wt,    // [1024][20736]
                       const float* __restrict__ bias,
                       float* __restrict__ U) {
  __shared__ __align__(16) __hip_bfloat16 As[128 * 64];
  __shared__ __align__(16) __hip_bfloat16 Bs[128 * 64];
  int l = blockIdx.x;
  int s = l >> 7;                 // super-row 0..8
  int w0 = l & 127;
  int xcd = w0 & 7;
  int j = w0 >> 3;                // 0..15
  int bm = s * 16 + xcd * 2 + (j & 1);   // 0..143
  int bn = j >> 1;                       // 0..7

  int tid = threadIdx.x;
  int lane = tid & 63, w = tid >> 6;
  int seg  = lane & 7;   // 16B segment within a row's 128B (8 bf16)
  int rsub = lane >> 3;  // 0..7  == (row & 7) for this lane's staged row
  int sseg = seg ^ rsub; // pre-swizzled source chunk (rule #21)

  // per-lane global source bases; rows r = w*32 + i*8 + rsub
  const __hip_bfloat16* abase[4];
  const __hip_bfloat16* bbase[4];
#pragma unroll
  for (int i = 0; i < 4; i++) {
    int r = w * 32 + i * 8 + rsub;
    int m = bm * 128 + r;
    int b = m / 144, rem = m % 144;
    int oy = rem / 12, ox = rem % 12;
    abase[i] = Apad + (((size_t)(b * 31 + oy * 2)) * 31 + ox * 2) * 256 + sseg * 8;
    int n = bn * 128 + r;
    bbase[i] = Wt + (size_t)n * 20736 + sseg * 8;
  }

  f32x4 acc[4][4];
#pragma unroll
  for (int mi = 0; mi < 4; mi++)
#pragma unroll
    for (int ni = 0; ni < 4; ni++)
#pragma unroll
      for (int r = 0; r < 4; r++) acc[mi][ni][r] = 0.f;

  int wm = w >> 1, wn = w & 1;
  int lrow = lane & 15;
  int lq = lane >> 4;          // quarter: which 8-elem chunk within K=32

  for (int pos = 0; pos < 81; pos++) {
    int ky = pos / 9, kx = pos % 9;
    size_t aoff = (size_t)(ky * 31 + kx) * 256;
    size_t boff = (size_t)pos * 256;
#pragma unroll
    for (int ci0 = 0; ci0 < 256; ci0 += 64) {
#pragma unroll
      for (int i = 0; i < 4; i++) {
        GLOAD_LDS16(abase[i] + aoff + ci0, &As[(w * 32 + i * 8) * 64]);
        GLOAD_LDS16(bbase[i] + boff + ci0, &Bs[(w * 32 + i * 8) * 64]);
      }
      __syncthreads();
#pragma unroll
      for (int ksub = 0; ksub < 2; ksub++) {
        s16x8 af[4], bf[4];
#pragma unroll
        for (int mi = 0; mi < 4; mi++) {
          int row = wm * 64 + mi * 16 + lrow;
          int c = (ksub * 4 + lq) ^ (row & 7);          // swizzled read chunk
          af[mi] = *(const s16x8*)(As + row * 64 + c * 8);
        }
#pragma unroll
        for (int ni = 0; ni < 4; ni++) {
          int row = wn * 64 + ni * 16 + lrow;
          int c = (ksub * 4 + lq) ^ (row & 7);
          bf[ni] = *(const s16x8*)(Bs + row * 64 + c * 8);
        }
#pragma unroll
        for (int mi = 0; mi < 4; mi++)
#pragma unroll
          for (int ni = 0; ni < 4; ni++)
            acc[mi][ni] = __builtin_amdgcn_mfma_f32_16x16x32_bf16(
                af[mi], bf[ni], acc[mi][ni], 0, 0, 0);
      }
      __syncthreads();
    }
  }

  // epilogue: D row = (lane>>4)*4 + reg, col = lane&15  [measured m89/m91]
#pragma unroll
  for (int mi = 0; mi < 4; mi++) {
    int mg = bm * 128 + wm * 64 + mi * 16 + ((lane >> 4) << 2);
#pragma unroll
    for (int ni = 0; ni < 4; ni++) {
      int ng = bn * 128 + wn * 64 + ni * 16 + (lane & 15);
      float bv = bias[ng];
#pragma unroll
      for (int r = 0; r < 4; r++)
        U[(size_t)(mg + r) * 1024 + ng] = acc[mi][ni][r] + bv;
    }
  }
}

// ---------------------------------------------------------------------------
// u_hat[b,n,kd] = sum_p w[n,kd,p] * u[b,n,p]; one block per capsule n.
// ---------------------------------------------------------------------------
__global__ void uhat_kernel(const float* __restrict__ u,
                            const float* __restrict__ w,
                            float* __restrict__ uhat) {
  int n = blockIdx.x;
  __shared__ float wsm[32 * 33];
  int t = threadIdx.x;
  for (int i = t; i < 1024; i += 256)
    wsm[(i >> 5) * 33 + (i & 31)] = w[(size_t)n * 1024 + i];
  __syncthreads();
  int kd = t & 31, bs = t >> 5;
  float wr[32];
#pragma unroll
  for (int p = 0; p < 32; p++) wr[p] = wsm[kd * 33 + p];
  for (int bp = 0; bp < 16; bp++) {
    int b = bp * 8 + bs;
    size_t off = ((size_t)b * NCAPS + n) * 32 + kd;
    float uval = u[off];
    float acc = 0.f;
#pragma unroll
    for (int p = 0; p < 32; p++) acc += wr[p] * __shfl(uval, p, 32);
    uhat[off] = acc;
  }
}

// ---------------------------------------------------------------------------
// routing pass: ITER 0 -> c = 0.5 (softmax of zeros)
//               ITER 1 -> a1 = u_hat.v1 (stored), c = softmax_k(a1)
//               ITER 2 -> c = softmax_k(a1 + u_hat.v2)
// ---------------------------------------------------------------------------
template <int ITER>
__global__ void routing_kernel(const float* __restrict__ uhat,
                               const float* __restrict__ v,
                               float* __restrict__ a1,
                               float* __restrict__ Spart) {
  int b = blockIdx.y;
  int t = threadIdx.x;
  int n = blockIdx.x * 256 + t;
  __shared__ float vs[32];
  __shared__ float wsum[4][33];
  if (ITER > 0) {
    if (t < 32) vs[t] = v[b * 32 + t];
    __syncthreads();
  }
  float uh[32];
  const float* up = uhat + ((size_t)b * NCAPS + n) * 32;
#pragma unroll
  for (int i = 0; i < 32; i += 4) {
    f32x4 tmp = *(const f32x4*)(up + i);
    uh[i + 0] = tmp[0]; uh[i + 1] = tmp[1];
    uh[i + 2] = tmp[2]; uh[i + 3] = tmp[3];
  }
  float c0 = 0.5f, c1 = 0.5f;
  if (ITER > 0) {
    float d0 = 0.f, d1 = 0.f;
#pragma unroll
    for (int d = 0; d < 16; d++) { d0 += uh[d] * vs[d]; d1 += uh[16 + d] * vs[16 + d]; }
    float b0, b1;
    size_t ai = ((size_t)b * NCAPS + n) * 2;
    if (ITER == 1) {
      a1[ai] = d0; a1[ai + 1] = d1;
      b0 = d0; b1 = d1;
    } else {
      b0 = a1[ai] + d0; b1 = a1[ai + 1] + d1;
    }
    float mx = fmaxf(b0, b1);
    float e0 = __expf(b0 - mx), e1 = __expf(b1 - mx);
    float inv = 1.f / (e0 + e1);
    c0 = e0 * inv; c1 = e1 * inv;
  }
  float val[32];
#pragma unroll
  for (int i = 0; i < 16; i++) { val[i] = c0 * uh[i]; val[16 + i] = c1 * uh[16 + i]; }
#pragma unroll
  for (int m = 1; m < 64; m <<= 1) {
#pragma unroll
    for (int i = 0; i < 32; i++) val[i] += __shfl_xor(val[i], m, 64);
  }
  int lane = t & 63, wid = t >> 6;
  if (lane == 0) {
#pragma unroll
    for (int i = 0; i < 32; i++) wsum[wid][i] = val[i];
  }
  __syncthreads();
  if (t < 32)
    Spart[((size_t)b * 18 + blockIdx.x) * 32 + t] =
        wsum[0][t] + wsum[1][t] + wsum[2][t] + wsum[3][t];
}

// ---------------------------------------------------------------------------
// squash: reduce 18 partials, v = |s|^2/(1+|s|^2) * s/(|s|+eps)
// ---------------------------------------------------------------------------
__global__ void squash_kernel(const float* __restrict__ Spart,
                              float* __restrict__ v,
                              const float* __restrict__ y,
                              float* __restrict__ vmask,
                              float* __restrict__ vout) {
  int t = threadIdx.x;            // t = b*2 + k
  float s[16];
#pragma unroll
  for (int d = 0; d < 16; d++) s[d] = 0.f;
  const float* p = Spart + (size_t)(t >> 1) * 18 * 32 + (t & 1) * 16;
  for (int ch = 0; ch < 18; ch++) {
#pragma unroll
    for (int d = 0; d < 16; d++) s[d] += p[ch * 32 + d];
  }
  float n2 = 0.f;
#pragma unroll
  for (int d = 0; d < 16; d++) n2 += s[d] * s[d];
  float nrm = sqrtf(n2);
  float f = n2 / (1.f + n2) / (nrm + 1e-7f);
#pragma unroll
  for (int d = 0; d < 16; d++) {
    float vd = s[d] * f;
    v[t * 16 + d] = vd;
    if (vout != nullptr) {
      vout[t * 16 + d] = vd;
      vmask[t * 16 + d] = y[t] * vd;
    }
  }
}

// ---------------------------------------------------------------------------
// decoder dense layer: Y[128,N] = act(X[128,K] @ Wd[K,N] + bias)
// R4: conflict-free staged writes (consecutive lanes -> consecutive bb) and
// f32x4 broadcast LDS reads (all 64 lanes same addr -> free; 4x fewer issues).
// block: 256 thr = 64 cols (tx) x 4 row-groups (ty); thread owns rows
// ty*32..ty*32+31. grid: N/64. ACT: 1 = relu, 2 = sigmoid
// ---------------------------------------------------------------------------
template <int ACT>
__global__ void dense_kernel(const float* __restrict__ X,
                             const float* __restrict__ Wd,
                             const float* __restrict__ bias,
                             float* __restrict__ Y, int K, int N) {
  __shared__ float xs[32][132];   // [kk][b]
  int tx = threadIdx.x & 63, ty = threadIdx.x >> 6;
  int j = blockIdx.x * 64 + tx;
  float acc[32];
#pragma unroll
  for (int i = 0; i < 32; i++) acc[i] = 0.f;
  for (int kc = 0; kc < K; kc += 32) {
    for (int idx = threadIdx.x; idx < 32 * 128; idx += 256) {
      int bb = idx & 127, kk = idx >> 7;           // lanes -> consecutive bb
      xs[kk][bb] = X[(size_t)bb * K + kc + kk];
    }
    __syncthreads();
    for (int kk = 0; kk < 32; kk++) {
      float wvv = Wd[(size_t)(kc + kk) * N + j];
#pragma unroll
      for (int i = 0; i < 8; i++) {
        f32x4 xv = *(const f32x4*)&xs[kk][ty * 32 + i * 4];   // broadcast read
        acc[i * 4 + 0] += xv[0] * wvv;
        acc[i * 4 + 1] += xv[1] * wvv;
        acc[i * 4 + 2] += xv[2] * wvv;
        acc[i * 4 + 3] += xv[3] * wvv;
      }
    }
    __syncthreads();
  }
  float bv = bias[j];
#pragma unroll
  for (int i = 0; i < 32; i++) {
    float r = acc[i] + bv;
    if (ACT == 1) r = fmaxf(r, 0.f);
    else          r = 1.f / (1.f + __expf(-r));
    Y[(size_t)(ty * 32 + i) * N + j] = r;
  }
}

// ---------------------------------------------------------------------------
extern "C" void kernel_launch(void* const* d_in, const int* in_sizes, int n_in,
                              void* d_out, int out_size, void* d_ws, size_t ws_size,
                              hipStream_t stream) {
  const float* input_x = (const float*)d_in[0];
  const float* y       = (const float*)d_in[1];
  const float* conv1_w = (const float*)d_in[2];
  const float* conv1_b = (const float*)d_in[3];
  const float* conv2_w = (const float*)d_in[4];
  const float* conv2_b = (const float*)d_in[5];
  const float* w_caps  = (const float*)d_in[6];
  const float* d1_w    = (const float*)d_in[7];
  const float* d1_b    = (const float*)d_in[8];
  const float* d2_w    = (const float*)d_in[9];
  const float* d2_b    = (const float*)d_in[10];
  const float* d3_w    = (const float*)d_in[11];
  const float* d3_b    = (const float*)d_in[12];
  float* out = (float*)d_out;

  // workspace carve-up
  char* ws = (char*)d_ws;
  size_t apad_bytes = (size_t)128 * 31 * 31 * 256 * 2;                 // 62.9 MB
  __hip_bfloat16* Apad = (__hip_bfloat16*)ws; ws += (apad_bytes + 255) & ~255ull;
  __hip_bfloat16* Wt   = (__hip_bfloat16*)ws; ws += 42467328;          // 1024*20736 bf16
  float* u     = (float*)ws; ws += 75497472;                           // 128*4608*32 f32
  float* uhat  = (float*)ws; ws += 75497472;                           // 128*4608*32 f32
  float* a1    = (float*)ws; ws += 4718592;                            // 128*4608*2 f32
  float* Spart = (float*)ws; ws += 294912;                             // 128*18*32 f32
  float* vbuf  = (float*)ws; ws += 16384;                              // 128*32 f32
  float* vmask = (float*)ws; ws += 16384;                              // 128*32 f32
  float* h1    = (float*)ws; ws += 131072;                             // 128*256 f32
  float* h2    = (float*)ws; ws += 262144;                             // 128*512 f32

  hipMemsetAsync(Apad, 0, apad_bytes, stream);   // zero padding borders
  transpose_w_kernel<<<dim3(324, 16), 256, 0, stream>>>(conv2_w, Wt);
  conv1_kernel<<<3072, 256, 0, stream>>>(input_x, conv1_w, conv1_b, Apad);
  conv2_mfma_kernel<<<1152, 256, 0, stream>>>(Apad, Wt, conv2_b, u);
  uhat_kernel<<<NCAPS, 256, 0, stream>>>(u, w_caps, uhat);

  routing_kernel<0><<<dim3(18, 128), 256, 0, stream>>>(uhat, nullptr, nullptr, Spart);
  squash_kernel<<<1, 256, 0, stream>>>(Spart, vbuf, nullptr, nullptr, nullptr);
  routing_kernel<1><<<dim3(18, 128), 256, 0, stream>>>(uhat, vbuf, a1, Spart);
  squash_kernel<<<1, 256, 0, stream>>>(Spart, vbuf, nullptr, nullptr, nullptr);
  routing_kernel<2><<<dim3(18, 128), 256, 0, stream>>>(uhat, vbuf, a1, Spart);
  // final squash: writes v into d_out[0:4096] and masked v for the decoder
  squash_kernel<<<1, 256, 0, stream>>>(Spart, vbuf, y, vmask, out);

  dense_kernel<1><<<4, 256, 0, stream>>>(vmask, d1_w, d1_b, h1, 32, 256);
  dense_kernel<1><<<8, 256, 0, stream>>>(h1, d2_w, d2_b, h2, 256, 512);
  dense_kernel<2><<<16, 256, 0, stream>>>(h2, d3_w, d3_b, out + 4096, 512, 1024);
}

// Round 5
// 1433.048 us; speedup vs baseline: 1.4013x; 1.1873x over previous
//
#include <hip/hip_runtime.h>
#include <hip/hip_bf16.h>

typedef __attribute__((ext_vector_type(8))) short s16x8;
typedef __attribute__((ext_vector_type(4))) int   i32x4;
typedef __attribute__((ext_vector_type(4))) float f32x4;

#define NCAPS 4608
#define BATCH 128

// async global->LDS helper (16B per lane, wave-uniform LDS dest)
#define GLOAD_LDS16(gp, lp)                                                   \
  __builtin_amdgcn_global_load_lds(                                           \
      (const __attribute__((address_space(1))) void*)(gp),                    \
      (__attribute__((address_space(3))) void*)(lp), 16, 0, 0)

// ---------------------------------------------------------------------------
// conv2 weights: (9*9*256, 1024) f32 -> transposed bf16 (1024, 20736)
// ---------------------------------------------------------------------------
__global__ void transpose_w_kernel(const float* __restrict__ W,
                                   __hip_bfloat16* __restrict__ Wt) {
  __shared__ float tile[64][65];
  int kt = blockIdx.x * 64;   // k tile (0..20735)
  int ct = blockIdx.y * 64;   // co tile (0..1023)
  for (int i = threadIdx.x; i < 64 * 64; i += 256) {
    int r = i >> 6, c = i & 63;
    tile[r][c] = W[(size_t)(kt + r) * 1024 + ct + c];
  }
  __syncthreads();
  for (int i = threadIdx.x; i < 64 * 64; i += 256) {
    int r = i >> 6, c = i & 63;
    Wt[(size_t)(ct + r) * 20736 + kt + c] = __float2bfloat16(tile[c][r]);
  }
}

// ---------------------------------------------------------------------------
// conv1: (128,32,32,1) x (9,9,1,256) VALID stride1 + bias + relu -> bf16
// writes into ZERO-PADDED layout [b][31][31][256], interior at (+3,+3)
// ---------------------------------------------------------------------------
__global__ void conv1_kernel(const float* __restrict__ x,
                             const float* __restrict__ w,
                             const float* __restrict__ bias,
                             __hip_bfloat16* __restrict__ outp) {
  int by = blockIdx.x;            // b*24 + y
  int b = by / 24, y = by % 24;
  __shared__ float patch[288];    // 9 rows x 32 cols
  for (int i = threadIdx.x; i < 288; i += 256) {
    int r = i >> 5, c = i & 31;
    patch[i] = x[(size_t)b * 1024 + (y + r) * 32 + c];
  }
  __syncthreads();
  int co = threadIdx.x;
  float bv = bias[co];
  float acc[24];
#pragma unroll
  for (int i = 0; i < 24; i++) acc[i] = bv;
#pragma unroll
  for (int ky = 0; ky < 9; ky++) {
    float row[32];
#pragma unroll
    for (int c = 0; c < 32; c++) row[c] = patch[ky * 32 + c];
#pragma unroll
    for (int kx = 0; kx < 9; kx++) {
      float wv = w[(ky * 9 + kx) * 256 + co];
#pragma unroll
      for (int xx = 0; xx < 24; xx++) acc[xx] += row[kx + xx] * wv;
    }
  }
  // padded store: [b][y+3][x+3][co]
  size_t obase = (((size_t)b * 31 + (y + 3)) * 31 + 3) * 256 + co;
#pragma unroll
  for (int xx = 0; xx < 24; xx++)
    outp[obase + (size_t)xx * 256] = __float2bfloat16(fmaxf(acc[xx], 0.f));
}

// ---------------------------------------------------------------------------
// conv2 as implicit GEMM, bf16 MFMA 16x16x32.
// R4: XCD-chunked super-row mapping (kept). R5: T3-minimum 2-phase pipeline:
// LDS double-buffer; issue next-tile global_load_lds BEFORE current compute;
// ONE __syncthreads() per K-step (its vmcnt(0)+lgkmcnt(0) drain lands after
// the MFMAs -> load latency hidden under compute). rule-#21 swizzle kept.
// ---------------------------------------------------------------------------
__global__ __launch_bounds__(256)
void conv2_mfma_kernel(const __hip_bfloat16* __restrict__ Apad,  // [128][31][31][256]
                       const __hip_bfloat16* __restrict__ Wt,    // [1024][20736]
                       const float* __restrict__ bias,
                       float* __restrict__ U) {
  __shared__ __align__(16) __hip_bfloat16 As[2][128 * 64];
  __shared__ __align__(16) __hip_bfloat16 Bs[2][128 * 64];
  int l = blockIdx.x;
  int s = l >> 7;                 // super-row 0..8
  int w0 = l & 127;
  int xcd = w0 & 7;
  int j = w0 >> 3;                // 0..15
  int bm = s * 16 + xcd * 2 + (j & 1);   // 0..143
  int bn = j >> 1;                       // 0..7

  int tid = threadIdx.x;
  int lane = tid & 63, w = tid >> 6;
  int seg  = lane & 7;   // 16B segment within a row's 128B (8 bf16)
  int rsub = lane >> 3;  // 0..7  == (row & 7) for this lane's staged row
  int sseg = seg ^ rsub; // pre-swizzled source chunk (rule #21)

  // per-lane global source bases; rows r = w*32 + i*8 + rsub
  const __hip_bfloat16* abase[4];
  const __hip_bfloat16* bbase[4];
#pragma unroll
  for (int i = 0; i < 4; i++) {
    int r = w * 32 + i * 8 + rsub;
    int m = bm * 128 + r;
    int b = m / 144, rem = m % 144;
    int oy = rem / 12, ox = rem % 12;
    abase[i] = Apad + (((size_t)(b * 31 + oy * 2)) * 31 + ox * 2) * 256 + sseg * 8;
    int n = bn * 128 + r;
    bbase[i] = Wt + (size_t)n * 20736 + sseg * 8;
  }

  f32x4 acc[4][4];
#pragma unroll
  for (int mi = 0; mi < 4; mi++)
#pragma unroll
    for (int ni = 0; ni < 4; ni++)
#pragma unroll
      for (int r = 0; r < 4; r++) acc[mi][ni][r] = 0.f;

  int wm = w >> 1, wn = w & 1;
  int lrow = lane & 15;
  int lq = lane >> 4;          // quarter: which 8-elem chunk within K=32

  // stage K-step ks into LDS buffer buf (8 async 16B loads per lane)
  auto STAGE = [&](int buf, int ks) {
    int pos = ks >> 2, ci0 = (ks & 3) << 6;
    int ky = pos / 9, kx = pos % 9;
    size_t aoff = (size_t)(ky * 31 + kx) * 256 + ci0;
    size_t boff = (size_t)pos * 256 + ci0;
#pragma unroll
    for (int i = 0; i < 4; i++) {
      GLOAD_LDS16(abase[i] + aoff, &As[buf][(w * 32 + i * 8) * 64]);
      GLOAD_LDS16(bbase[i] + boff, &Bs[buf][(w * 32 + i * 8) * 64]);
    }
  };

  STAGE(0, 0);
  __syncthreads();          // drain prologue loads
  int cur = 0;
  for (int ks = 0; ks < 324; ++ks) {
    if (ks < 323) STAGE(cur ^ 1, ks + 1);   // prefetch flies during compute
    const __hip_bfloat16* Ac = As[cur];
    const __hip_bfloat16* Bc = Bs[cur];
#pragma unroll
    for (int ksub = 0; ksub < 2; ksub++) {
      s16x8 af[4], bf[4];
#pragma unroll
      for (int mi = 0; mi < 4; mi++) {
        int row = wm * 64 + mi * 16 + lrow;
        int c = (ksub * 4 + lq) ^ (row & 7);          // swizzled read chunk
        af[mi] = *(const s16x8*)(Ac + row * 64 + c * 8);
      }
#pragma unroll
      for (int ni = 0; ni < 4; ni++) {
        int row = wn * 64 + ni * 16 + lrow;
        int c = (ksub * 4 + lq) ^ (row & 7);
        bf[ni] = *(const s16x8*)(Bc + row * 64 + c * 8);
      }
#pragma unroll
      for (int mi = 0; mi < 4; mi++)
#pragma unroll
        for (int ni = 0; ni < 4; ni++)
          acc[mi][ni] = __builtin_amdgcn_mfma_f32_16x16x32_bf16(
              af[mi], bf[ni], acc[mi][ni], 0, 0, 0);
    }
    __syncthreads();        // one barrier/K-step; drains prefetch after MFMAs
    cur ^= 1;
  }

  // epilogue: D row = (lane>>4)*4 + reg, col = lane&15  [measured m89/m91]
#pragma unroll
  for (int mi = 0; mi < 4; mi++) {
    int mg = bm * 128 + wm * 64 + mi * 16 + ((lane >> 4) << 2);
#pragma unroll
    for (int ni = 0; ni < 4; ni++) {
      int ng = bn * 128 + wn * 64 + ni * 16 + (lane & 15);
      float bv = bias[ng];
#pragma unroll
      for (int r = 0; r < 4; r++)
        U[(size_t)(mg + r) * 1024 + ng] = acc[mi][ni][r] + bv;
    }
  }
}

// ---------------------------------------------------------------------------
// u_hat[b,n,kd] = sum_p w[n,kd,p] * u[b,n,p]; one block per capsule n.
// ---------------------------------------------------------------------------
__global__ void uhat_kernel(const float* __restrict__ u,
                            const float* __restrict__ w,
                            float* __restrict__ uhat) {
  int n = blockIdx.x;
  __shared__ float wsm[32 * 33];
  int t = threadIdx.x;
  for (int i = t; i < 1024; i += 256)
    wsm[(i >> 5) * 33 + (i & 31)] = w[(size_t)n * 1024 + i];
  __syncthreads();
  int kd = t & 31, bs = t >> 5;
  float wr[32];
#pragma unroll
  for (int p = 0; p < 32; p++) wr[p] = wsm[kd * 33 + p];
  for (int bp = 0; bp < 16; bp++) {
    int b = bp * 8 + bs;
    size_t off = ((size_t)b * NCAPS + n) * 32 + kd;
    float uval = u[off];
    float acc = 0.f;
#pragma unroll
    for (int p = 0; p < 32; p++) acc += wr[p] * __shfl(uval, p, 32);
    uhat[off] = acc;
  }
}

// ---------------------------------------------------------------------------
// MEGA: routing (3 iters) + squash + masked decoder, ONE kernel.
// grid = 128 (one block per batch b), block = 512 threads (8 waves).
// Each thread owns 9 capsules (n = t + 512*i). a1 logits cached in registers.
// Per iter: partial c*u_hat sums -> wave shfl reduce -> LDS 8x32 -> squash on
// 32 lanes (16-lane shfl_xor for |s|^2) -> v in LDS. Decoder per-b chain:
// 32 -> 256 relu -> 512 relu -> 1024 sigmoid, activations staged in LDS.
// ---------------------------------------------------------------------------
__global__ __launch_bounds__(512)
void routing_decoder_kernel(const float* __restrict__ uhat,
                            const float* __restrict__ y,
                            const float* __restrict__ d1_w,
                            const float* __restrict__ d1_b,
                            const float* __restrict__ d2_w,
                            const float* __restrict__ d2_b,
                            const float* __restrict__ d3_w,
                            const float* __restrict__ d3_b,
                            float* __restrict__ out) {
  int b = blockIdx.x;
  int t = threadIdx.x;
  int lane = t & 63, wid = t >> 6;
  __shared__ float vls[32];
  __shared__ float red[8][32];
  __shared__ float vms[32];
  __shared__ float h1s[256];
  __shared__ float h2s[512];
  float a1c0[9], a1c1[9];        // cached logits (register-resident)
  const float* ub = uhat + (size_t)b * NCAPS * 32;

  for (int it = 0; it < 3; ++it) {
    float part[32];
#pragma unroll
    for (int d = 0; d < 32; ++d) part[d] = 0.f;
    float v0[16], v1[16];
    if (it > 0) {
#pragma unroll
      for (int d = 0; d < 16; ++d) { v0[d] = vls[d]; v1[d] = vls[16 + d]; }
    }
#pragma unroll
    for (int i = 0; i < 9; ++i) {
      int n = t + 512 * i;
      const float* up = ub + (size_t)n * 32;
      float uh[32];
#pragma unroll
      for (int q = 0; q < 8; ++q) {
        f32x4 tmp = *(const f32x4*)(up + q * 4);
        uh[q * 4 + 0] = tmp[0]; uh[q * 4 + 1] = tmp[1];
        uh[q * 4 + 2] = tmp[2]; uh[q * 4 + 3] = tmp[3];
      }
      float c0 = 0.5f, c1 = 0.5f;
      if (it > 0) {
        float d0 = 0.f, d1 = 0.f;
#pragma unroll
        for (int d = 0; d < 16; ++d) { d0 += uh[d] * v0[d]; d1 += uh[16 + d] * v1[d]; }
        float b0, b1;
        if (it == 1) { a1c0[i] = d0; a1c1[i] = d1; b0 = d0; b1 = d1; }
        else         { b0 = a1c0[i] + d0; b1 = a1c1[i] + d1; }
        float mx = fmaxf(b0, b1);
        float e0 = __expf(b0 - mx), e1 = __expf(b1 - mx);
        float inv = 1.f / (e0 + e1);
        c0 = e0 * inv; c1 = e1 * inv;
      }
#pragma unroll
      for (int d = 0; d < 16; ++d) {
        part[d]      += c0 * uh[d];
        part[16 + d] += c1 * uh[16 + d];
      }
    }
    // wave butterfly reduce (64 lanes)
#pragma unroll
    for (int m = 1; m < 64; m <<= 1)
#pragma unroll
      for (int d = 0; d < 32; ++d) part[d] += __shfl_xor(part[d], m, 64);
    __syncthreads();               // prior-iter red reads / vls reads done
    if (lane == 0)
#pragma unroll
      for (int d = 0; d < 32; ++d) red[wid][d] = part[d];
    __syncthreads();
    if (t < 32) {
      float sd = 0.f;
#pragma unroll
      for (int w2 = 0; w2 < 8; ++w2) sd += red[w2][t];
      float p = sd * sd;
#pragma unroll
      for (int m = 1; m < 16; m <<= 1) p += __shfl_xor(p, m, 64);  // 16-lane group
      float f = p / (1.f + p) / (sqrtf(p) + 1e-7f);
      vls[t] = sd * f;
    }
    __syncthreads();
  }

  // v output + mask
  if (t < 32) {
    float vv = vls[t];
    out[(size_t)b * 32 + t] = vv;
    vms[t] = y[b * 2 + (t >> 4)] * vv;
  }
  __syncthreads();
  // decoder layer 1: 32 -> 256 relu
  if (t < 256) {
    float acc = d1_b[t];
#pragma unroll
    for (int k = 0; k < 32; ++k) acc += vms[k] * d1_w[k * 256 + t];
    h1s[t] = fmaxf(acc, 0.f);
  }
  __syncthreads();
  // decoder layer 2: 256 -> 512 relu
  {
    float acc = d2_b[t];
    for (int k = 0; k < 256; ++k) acc += h1s[k] * d2_w[k * 512 + t];
    h2s[t] = fmaxf(acc, 0.f);
  }
  __syncthreads();
  // decoder layer 3: 512 -> 1024 sigmoid
  float* rout = out + 4096 + (size_t)b * 1024;
#pragma unroll
  for (int jj = 0; jj < 2; ++jj) {
    int jcol = t + jj * 512;
    float acc = d3_b[jcol];
    for (int k = 0; k < 512; ++k) acc += h2s[k] * d3_w[k * 1024 + jcol];
    rout[jcol] = 1.f / (1.f + __expf(-acc));
  }
}

// ---------------------------------------------------------------------------
extern "C" void kernel_launch(void* const* d_in, const int* in_sizes, int n_in,
                              void* d_out, int out_size, void* d_ws, size_t ws_size,
                              hipStream_t stream) {
  const float* input_x = (const float*)d_in[0];
  const float* y       = (const float*)d_in[1];
  const float* conv1_w = (const float*)d_in[2];
  const float* conv1_b = (const float*)d_in[3];
  const float* conv2_w = (const float*)d_in[4];
  const float* conv2_b = (const float*)d_in[5];
  const float* w_caps  = (const float*)d_in[6];
  const float* d1_w    = (const float*)d_in[7];
  const float* d1_b    = (const float*)d_in[8];
  const float* d2_w    = (const float*)d_in[9];
  const float* d2_b    = (const float*)d_in[10];
  const float* d3_w    = (const float*)d_in[11];
  const float* d3_b    = (const float*)d_in[12];
  float* out = (float*)d_out;

  // workspace carve-up (~256 MB)
  char* ws = (char*)d_ws;
  size_t apad_bytes = (size_t)128 * 31 * 31 * 256 * 2;                 // 62.9 MB
  __hip_bfloat16* Apad = (__hip_bfloat16*)ws; ws += (apad_bytes + 255) & ~255ull;
  __hip_bfloat16* Wt   = (__hip_bfloat16*)ws; ws += 42467328;          // 1024*20736 bf16
  float* u     = (float*)ws; ws += 75497472;                           // 128*4608*32 f32
  float* uhat  = (float*)ws; ws += 75497472;                           // 128*4608*32 f32

  hipMemsetAsync(Apad, 0, apad_bytes, stream);   // zero padding borders
  transpose_w_kernel<<<dim3(324, 16), 256, 0, stream>>>(conv2_w, Wt);
  conv1_kernel<<<3072, 256, 0, stream>>>(input_x, conv1_w, conv1_b, Apad);
  conv2_mfma_kernel<<<1152, 256, 0, stream>>>(Apad, Wt, conv2_b, u);
  uhat_kernel<<<NCAPS, 256, 0, stream>>>(u, w_caps, uhat);
  routing_decoder_kernel<<<128, 512, 0, stream>>>(uhat, y, d1_w, d1_b, d2_w,
                                                  d2_b, d3_w, d3_b, out);
}